// Round 8
// baseline (286.698 us; speedup 1.0000x reference)
//
#include <hip/hip_runtime.h>
#include <cstdint>
#include <cstddef>

#define BN_EPS 1e-5f
#define BATCH 8192

typedef unsigned long long u64;
typedef uint32_t u32;
typedef int v4i __attribute__((ext_vector_type(4)));
typedef int v16i __attribute__((ext_vector_type(16)));

// float <-> total-order key (ascending with float order on finites)
__device__ __forceinline__ u32 f2k(float f) {
    u32 u = __float_as_uint(f);
    return (u >> 31) ? ~u : (u | 0x80000000u);
}
__device__ __forceinline__ float k2f(u32 k) {
    u32 u = (k & 0x80000000u) ? (k ^ 0x80000000u) : ~k;
    return __uint_as_float(u);
}
// exact fp32 BN chain — bit-identical to the reference epilogue semantics
__device__ __forceinline__ float bn_eval(float conv, float B, float iv, float sh) {
    return __fadd_rn(__fmul_rn(__fadd_rn(conv, B), iv), sh);
}

// ---------------- one merged prep kernel ----------------
__global__ __launch_bounds__(256) void prep_all(
    const float* w1, const float* b1, const float* w2, const float* b2,
    const float* w3, const float* b3, const float* w4, const float* b4,
    const float* wf,
    const float* g1, const float* be1, const float* m1, const float* v1,
    const float* g2, const float* be2, const float* m2, const float* v2,
    const float* g3, const float* be3, const float* m3, const float* v3,
    const float* g4, const float* be4, const float* m4, const float* v4,
    float* s1f, float* T1, u32* wt2w, int* T2,
    uint4* b3i8, int* C3, u64* wt4, int* T4, u64* wtf) {
    int t = blockIdx.x * 256 + threadIdx.x;

    if (t < 384) {
        int co = t / 12, k = t % 12;
        float val = 0.f;
        if (k < 9) {
            float iv = g1[co] * rsqrtf(v1[co] + BN_EPS);
            float d = (iv < 0.f) ? -1.f : 1.f;
            val = ((w1[co * 9 + k] >= 0.f) ? 1.f : -1.f) * d;
        }
        s1f[t] = val;
    } else if (t < 416) {
        int co = t - 384;
        float iv = g1[co] * rsqrtf(v1[co] + BN_EPS);
        float sh = be1[co] - m1[co] * iv;
        float B = b1[co];
        bool flip = (iv < 0.f);
        auto pred = [&](float sp) {
            float sum = flip ? -sp : sp;
            return bn_eval(sum, B, iv, sh) >= 0.f;
        };
        u32 lo = f2k(-3.0e38f), hi = f2k(3.0e38f);
        float Tv;
        if (pred(k2f(lo))) Tv = k2f(lo);
        else if (!pred(k2f(hi))) Tv = __uint_as_float(0x7F800000u);
        else {
            while (hi - lo > 1u) {
                u32 mid = lo + ((hi - lo) >> 1);
                if (pred(k2f(mid))) hi = mid; else lo = mid;
            }
            Tv = k2f(hi);
        }
        T1[co] = Tv;
    } else if (t < 608) {
        int idx = t - 416;
        int co = idx / 3, kw = idx % 3;
        float iv = g2[co] * rsqrtf(v2[co] + BN_EPS);
        bool flip = (iv < 0.f);
        u32 wb = 0;
        for (int ci = 0; ci < 32; ++ci)
            wb |= (u32)((w2[(co * 32 + ci) * 3 + kw] >= 0.f) != flip) << ci;
        wt2w[co * 4 + kw] = wb;
    } else if (t < 800) {
        int idx = t - 608;
        int co = idx & 63, cls = idx >> 6;
        float iv = g2[co] * rsqrtf(v2[co] + BN_EPS);
        float sh = be2[co] - m2[co] * iv;
        float B = b2[co];
        bool flip = (iv < 0.f);
        int spur = 0, nv = 3;
        if (cls == 1) { nv = 2; for (int ci = 0; ci < 32; ++ci) spur += (int)((w2[(co * 32 + ci) * 3 + 0] >= 0.f) != flip); }
        if (cls == 2) { nv = 2; for (int ci = 0; ci < 32; ++ci) spur += (int)((w2[(co * 32 + ci) * 3 + 2] >= 0.f) != flip); }
        int maxp = 32 * nv + spur;
        int T = -1;
        for (int p = 0; p <= maxp; ++p) {
            int conv = flip ? (2 * (p - spur) - 32 * nv) : (32 * nv - 2 * (p - spur));
            float y = bn_eval((float)conv, B, iv, sh);
            if ((y >= 0.f) && (T == p - 1)) T = p;
        }
        T2[cls * 64 + co] = T;
    } else if (t < 2336) {
        int idx = t - 800;
        int q = idx >> 7, n = idx & 127;
        float iv = g3[n] * rsqrtf(v3[n] + BN_EPS);
        bool flip = (iv < 0.f);
        int kw = q >> 2, ci0 = (q & 3) * 16;
        u32 wd[4] = {0, 0, 0, 0};
        for (int j = 0; j < 16; ++j) {
            int ci = ci0 + j;
            bool pos = (w3[(n * 64 + ci) * 3 + kw] >= 0.f) != flip;
            u32 byte = pos ? 0x01u : 0xFFu;
            wd[j >> 2] |= byte << (8 * (j & 3));
        }
        b3i8[idx] = make_uint4(wd[0], wd[1], wd[2], wd[3]);
    } else if (t < 2464) {
        int co = t - 2336;
        float iv = g3[co] * rsqrtf(v3[co] + BN_EPS);
        float sh = be3[co] - m3[co] * iv;
        float B = b3[co];
        int C = 1000;
        if (iv >= 0.f) {
            for (int v = -192; v <= 192; v += 2)
                if (bn_eval((float)v, B, iv, sh) >= 0.f) { C = v; break; }
        } else {
            for (int v = 192; v >= -192; v -= 2)
                if (bn_eval((float)v, B, iv, sh) >= 0.f) { C = -v; break; }
        }
        C3[co] = C;
    } else if (t < 4000) {
        int idx = t - 2464;
        int j = idx & 1, ch = idx >> 1;
        int co = ch / 6, h = ch % 6;
        float iv = g4[co] * rsqrtf(v4[co] + BN_EPS);
        bool flip = (iv < 0.f);
        u64 wb = 0;
        for (int cb = 0; cb < 64; ++cb) {
            int ci = j * 64 + cb;
            wb |= (u64)((w4[(co * 128 + ci) * 6 + h] >= 0.f) != flip) << cb;
        }
        wt4[idx] = wb;
    } else if (t < 4128) {
        int co = t - 4000;
        float iv = g4[co] * rsqrtf(v4[co] + BN_EPS);
        float sh = be4[co] - m4[co] * iv;
        float B = b4[co];
        bool flip = (iv < 0.f);
        int T = -1;
        for (int p = 0; p <= 768; ++p) {
            int conv = flip ? (2 * p - 768) : (768 - 2 * p);
            float y = bn_eval((float)conv, B, iv, sh);
            if ((y >= 0.f) && (T == p - 1)) T = p;
        }
        T4[co] = T;
    } else if (t < 4448) {
        int idx = t - 4128;
        int o = idx / 32, wi = idx % 32;
        u64 wb = 0;
        for (int fb = 0; fb < 64; ++fb)
            wb |= (u64)(wf[o * 2048 + wi * 64 + fb] >= 0.f) << fb;
        wtf[idx] = wb;
    }
}

// ---------------- fused layer1+layer2 (verified R7 structure) ----------------
#define L12_ROWS 8
__global__ __launch_bounds__(256) void layer12_kernel(
    const float* __restrict__ x, const float4* __restrict__ s1p, const float* __restrict__ T1,
    const uint4* __restrict__ wt2v, const int* __restrict__ T2, u64* __restrict__ a2) {
    __shared__ float sX[L12_ROWS][144];
    __shared__ u32 sA1[L12_ROWS][32];
    __shared__ uint4 sW[64];
    __shared__ int sT2[192];
    int t = threadIdx.x;
    int bh0 = blockIdx.x * L12_ROWS;
    for (int i = t; i < L12_ROWS * 144; i += 256) {
        int r = i / 144, c = i % 144;
        float v = 0.f;
        if (c >= 4 && c < 132) v = x[(size_t)(bh0 + r) * 128 + (c - 4)];
        sX[r][c] = v;
    }
    if (t < 64) sW[t] = wt2v[t];
    if (t < 192) sT2[t] = T2[t];

    int co = t & 31, lane = t & 63;
    float4 wa = s1p[co * 3 + 0];
    float4 wb = s1p[co * 3 + 1];
    float wc = s1p[co * 3 + 2].x;
    float Tt = T1[co];
    __syncthreads();

    int rr = t >> 5;
    const float* xr = sX[rr];
    float4 A0 = *(const float4*)&xr[0];
    float4 A1 = *(const float4*)&xr[4];
    float4 A2 = *(const float4*)&xr[8];
    u32 myword = 0;
    for (int wp = 0; wp < 32; ++wp) {
        float sum0 = 0.f, sum1 = 0.f;
        sum0 = fmaf(wa.x, A0.x, sum0);  sum1 = fmaf(wa.x, A0.z, sum1);
        sum0 = fmaf(wa.y, A0.y, sum0);  sum1 = fmaf(wa.y, A0.w, sum1);
        sum0 = fmaf(wa.z, A0.z, sum0);  sum1 = fmaf(wa.z, A1.x, sum1);
        sum0 = fmaf(wa.w, A0.w, sum0);  sum1 = fmaf(wa.w, A1.y, sum1);
        sum0 = fmaf(wb.x, A1.x, sum0);  sum1 = fmaf(wb.x, A1.z, sum1);
        sum0 = fmaf(wb.y, A1.y, sum0);  sum1 = fmaf(wb.y, A1.w, sum1);
        sum0 = fmaf(wb.z, A1.z, sum0);  sum1 = fmaf(wb.z, A2.x, sum1);
        sum0 = fmaf(wb.w, A1.w, sum0);  sum1 = fmaf(wb.w, A2.y, sum1);
        sum0 = fmaf(wc,   A2.x, sum0);  sum1 = fmaf(wc,   A2.z, sum1);
        bool pred = (sum0 >= Tt) || (sum1 >= Tt);
        u64 mk = __ballot(pred);
        u32 hw = (lane < 32) ? (u32)mk : (u32)(mk >> 32);
        if ((lane & 31) == wp) myword = hw;
        A0 = A1; A1 = A2;
        A2 = *(const float4*)&xr[4 * wp + 12];
    }
    sA1[((t >> 6) << 1) + (lane >> 5)][lane & 31] = myword;
    __syncthreads();

    int r = t >> 5, wp = t & 31;
    u32 am = sA1[r][wp];
    u32 al = (wp > 0) ? sA1[r][wp - 1] : 0u;
    u32 ar = (wp < 31) ? sA1[r][wp + 1] : 0u;
    const int* Tp = &sT2[(wp == 0) ? 64 : ((wp == 31) ? 128 : 0)];
    u64 word2 = 0;
#pragma unroll
    for (int c = 0; c < 64; ++c) {
        uint4 wv = sW[c];
        int p = __popc(al ^ wv.x) + __popc(am ^ wv.y) + __popc(ar ^ wv.z);
        word2 |= (u64)(p <= Tp[c]) << c;
    }
    a2[(size_t)(bh0 + r) * 32 + wp] = word2;
}

// ---------------- layer 3: i8 MFMA conv, 2-row pairing for B-fragment reuse ----------------
#define L3_ROWS 4
__global__ __launch_bounds__(256) void layer3_mfma(
    const u64* __restrict__ a2, const uint4* __restrict__ b3i8, const int* __restrict__ C3,
    u32* __restrict__ a3u32) {
    __shared__ uint4 sB[12 * 128];
    __shared__ u64 sLUT[256];
    __shared__ int sC3[128];
    int t = threadIdx.x;
    for (int i = t; i < 1536; i += 256) sB[i] = b3i8[i];
    {
        u32 b = t & 255;
        u64 e = 0;
#pragma unroll
        for (int j = 0; j < 8; ++j)
            e |= (((b >> j) & 1) ? 0x01ull : 0xFFull) << (8 * j);
        if (t < 256) sLUT[t] = e;
    }
    if (t < 128) sC3[t] = C3[t];
    __syncthreads();

    int wv = t >> 6, lane = t & 63, m = lane & 31, half = lane >> 5;
    int rowBase = (blockIdx.x * 4 + wv) * L3_ROWS;
    const int prTab[8] = {0, 1, 4, 5, 8, 9, 12, 13};

    for (int pr2 = 0; pr2 < L3_ROWS / 2; ++pr2) {
        int bh0 = rowBase + 2 * pr2;
        v4i A0[6], A1[6];
#pragma unroll
        for (int rr = 0; rr < 2; ++rr) {
            u64 aw = a2[(size_t)(bh0 + rr) * 32 + m];
            u64 wm1 = __shfl(aw, m - 1);
            u64 wp1 = __shfl(aw, m + 1);
            v4i* A = rr ? A1 : A0;
#pragma unroll
            for (int kk = 0; kk < 6; ++kk) {
                const int kw = kk >> 1;
                u64 word = (kw == 0) ? wm1 : ((kw == 1) ? aw : wp1);
                bool valid = !((kw == 0 && m == 0) || (kw == 2 && m == 31));
                int ci0 = ((kk & 1) << 5) + (half << 4);
                u32 bits = (u32)(word >> ci0) & 0xFFFFu;
                u64 lo = sLUT[bits & 0xFF];
                u64 hi = sLUT[bits >> 8];
                if (!valid) { lo = 0; hi = 0; }
                union { u64 q[2]; v4i v; } u;
                u.q[0] = lo; u.q[1] = hi;
                A[kk] = u.v;
            }
        }

        u32 outv0 = 0, outv1 = 0;
#pragma unroll
        for (int nt = 0; nt < 4; ++nt) {
            v16i acc0, acc1;
#pragma unroll
            for (int i = 0; i < 16; ++i) { acc0[i] = 0; acc1[i] = 0; }
#pragma unroll
            for (int kk = 0; kk < 6; ++kk) {
                int q = kk * 2 + half;
                union { uint4 u4; v4i v; } bu;
                bu.u4 = sB[q * 128 + nt * 32 + m];
                acc0 = __builtin_amdgcn_mfma_i32_32x32x32_i8(A0[kk], bu.v, acc0, 0, 0, 0);
                acc1 = __builtin_amdgcn_mfma_i32_32x32x32_i8(A1[kk], bu.v, acc1, 0, 0, 0);
            }
            int tc = sC3[nt * 32 + m];
#pragma unroll
            for (int rp = 0; rp < 8; ++rp) {
                int LA = (nt << 4) | prTab[rp];
                int LB = LA + 2;
                {
                    bool c = (acc0[2 * rp] >= tc) || (acc0[2 * rp + 1] >= tc);
                    u64 mk = __ballot(c);
                    outv0 = (lane == LA) ? (u32)mk : outv0;
                    outv0 = (lane == LB) ? (u32)(mk >> 32) : outv0;
                }
                {
                    bool c = (acc1[2 * rp] >= tc) || (acc1[2 * rp + 1] >= tc);
                    u64 mk = __ballot(c);
                    outv1 = (lane == LA) ? (u32)mk : outv1;
                    outv1 = (lane == LB) ? (u32)(mk >> 32) : outv1;
                }
            }
        }
        int oidx = ((lane & 15) << 2) + (lane >> 4);
        a3u32[(size_t)bh0 * 64 + oidx] = outv0;
        a3u32[(size_t)(bh0 + 1) * 64 + oidx] = outv1;
    }
}

// ---------------- layer 4 (6x1 conv) + FC (2048->10) ----------------
__global__ __launch_bounds__(256) void layer4_fc_kernel(
    const u64* __restrict__ a3, const u64* __restrict__ wt4, const int* __restrict__ T4,
    const u64* __restrict__ wtf, const float* __restrict__ bf, float* __restrict__ out) {
    __shared__ u64 sW4[1536];
    __shared__ u64 sWf[320];
    __shared__ u64 sFeat[16][32];
    __shared__ int sT[128];
    __shared__ float sBf[10];
    int t = threadIdx.x;
    {
        ulonglong2* d = (ulonglong2*)sW4;
        const ulonglong2* s = (const ulonglong2*)wt4;
        for (int i = t; i < 768; i += 256) d[i] = s[i];
        ulonglong2* df = (ulonglong2*)sWf;
        const ulonglong2* sf = (const ulonglong2*)wtf;
        if (t < 160) df[t] = sf[t];
    }
    if (t < 128) sT[t] = T4[t];
    if (t < 10) sBf[t] = bf[t];
    __syncthreads();
    int bb = t >> 4, w = t & 15, lane = t & 63, g = lane >> 4;
    int b = blockIdx.x * 16 + bb;
    u64 av[12];
#pragma unroll
    for (int h = 0; h < 6; ++h) {
        av[h * 2 + 0] = a3[(size_t)b * 192 + h * 32 + w * 2 + 0];
        av[h * 2 + 1] = a3[(size_t)b * 192 + h * 32 + w * 2 + 1];
    }
    u64 acc = 0;
#pragma unroll 8
    for (int c = 0; c < 128; ++c) {
        const u64* wr = &sW4[c * 12];
        int p = 0;
#pragma unroll
        for (int q = 0; q < 12; ++q) p += __popcll(av[q] ^ wr[q]);
        u64 mk = __ballot(p <= sT[c]);
        u64 field = (mk >> (g * 16)) & 0xFFFFull;
        acc |= field << ((c & 3) << 4);
        if ((c & 3) == 3) {
            if (w == 0) sFeat[bb][c >> 2] = acc;
            acc = 0;
        }
    }
    __syncthreads();
    if (t < 160) {
        int fb = t / 10, o = t % 10;
        int p = 0;
#pragma unroll
        for (int wi = 0; wi < 32; ++wi) p += __popcll(sFeat[fb][wi] ^ sWf[o * 32 + wi]);
        out[(size_t)(blockIdx.x * 16 + fb) * 10 + o] = __fadd_rn((float)(2048 - 2 * p), sBf[o]);
    }
}

// ---------------- launch ----------------
extern "C" void kernel_launch(void* const* d_in, const int* in_sizes, int n_in,
                              void* d_out, int out_size, void* d_ws, size_t ws_size,
                              hipStream_t stream) {
    const float* x  = (const float*)d_in[0];
    const float* w1 = (const float*)d_in[1];  const float* b1 = (const float*)d_in[2];
    const float* w2 = (const float*)d_in[3];  const float* b2 = (const float*)d_in[4];
    const float* w3 = (const float*)d_in[5];  const float* b3 = (const float*)d_in[6];
    const float* w4 = (const float*)d_in[7];  const float* b4 = (const float*)d_in[8];
    const float* g1 = (const float*)d_in[9];  const float* be1 = (const float*)d_in[10];
    const float* m1 = (const float*)d_in[11]; const float* v1 = (const float*)d_in[12];
    const float* g2 = (const float*)d_in[13]; const float* be2 = (const float*)d_in[14];
    const float* m2 = (const float*)d_in[15]; const float* v2 = (const float*)d_in[16];
    const float* g3 = (const float*)d_in[17]; const float* be3 = (const float*)d_in[18];
    const float* m3 = (const float*)d_in[19]; const float* v3 = (const float*)d_in[20];
    const float* g4 = (const float*)d_in[21]; const float* be4 = (const float*)d_in[22];
    const float* m4 = (const float*)d_in[23]; const float* v4 = (const float*)d_in[24];
    const float* wf = (const float*)d_in[25]; const float* bf = (const float*)d_in[26];
    float* out = (float*)d_out;

    char* ws = (char*)d_ws;
    u64* a2 = (u64*)(ws + 0);                 // 12582912 B
    u64* a3 = (u64*)(ws + 12582912);          // 12582912 B
    const size_t S = 25165824;
    uint4* b3i8 = (uint4*)(ws + S + 0);       // 24576 B
    u64*  wt4  = (u64*) (ws + S + 24576);     // 12288 B
    u64*  wtf  = (u64*) (ws + S + 36864);     // 2560 B
    u32*  wt2w = (u32*) (ws + S + 39424);     // 1024 B
    float* s1f = (float*)(ws + S + 40448);    // 1536 B
    float* T1  = (float*)(ws + S + 41984);    // 128 B
    int*  T2   = (int*)  (ws + S + 42112);    // 768 B
    int*  C3   = (int*)  (ws + S + 42880);    // 512 B
    int*  T4   = (int*)  (ws + S + 43392);    // 512 B

    prep_all<<<18, 256, 0, stream>>>(w1, b1, w2, b2, w3, b3, w4, b4, wf,
                                     g1, be1, m1, v1, g2, be2, m2, v2,
                                     g3, be3, m3, v3, g4, be4, m4, v4,
                                     s1f, T1, wt2w, T2, b3i8, C3, wt4, T4, wtf);

    layer12_kernel<<<(BATCH * 6) / L12_ROWS, 256, 0, stream>>>(
        x, (const float4*)s1f, T1, (const uint4*)wt2w, T2, a2);
    layer3_mfma<<<(BATCH * 6) / (4 * L3_ROWS), 256, 0, stream>>>(a2, b3i8, C3, (u32*)a3);
    layer4_fc_kernel<<<BATCH / 16, 256, 0, stream>>>(a3, wt4, T4, wtf, bf, out);
}

// Round 9
// 284.377 us; speedup vs baseline: 1.0082x; 1.0082x over previous
//
#include <hip/hip_runtime.h>
#include <cstdint>
#include <cstddef>

#define BN_EPS 1e-5f
#define BATCH 8192

typedef unsigned long long u64;
typedef uint32_t u32;
typedef int v4i __attribute__((ext_vector_type(4)));
typedef int v16i __attribute__((ext_vector_type(16)));

// float <-> total-order key (ascending with float order on finites)
__device__ __forceinline__ u32 f2k(float f) {
    u32 u = __float_as_uint(f);
    return (u >> 31) ? ~u : (u | 0x80000000u);
}
__device__ __forceinline__ float k2f(u32 k) {
    u32 u = (k & 0x80000000u) ? (k ^ 0x80000000u) : ~k;
    return __uint_as_float(u);
}
// exact fp32 BN chain — bit-identical to the reference epilogue semantics
__device__ __forceinline__ float bn_eval(float conv, float B, float iv, float sh) {
    return __fadd_rn(__fmul_rn(__fadd_rn(conv, B), iv), sh);
}

// ---------------- one merged prep kernel ----------------
__global__ __launch_bounds__(256) void prep_all(
    const float* w1, const float* b1, const float* w2, const float* b2,
    const float* w3, const float* b3, const float* w4, const float* b4,
    const float* wf,
    const float* g1, const float* be1, const float* m1, const float* v1,
    const float* g2, const float* be2, const float* m2, const float* v2,
    const float* g3, const float* be3, const float* m3, const float* v3,
    const float* g4, const float* be4, const float* m4, const float* v4,
    float* s1f, float* T1, uint4* b2i8, int* C2,
    uint4* b3i8, int* C3, u64* wt4, int* T4, u64* wtf) {
    int t = blockIdx.x * 256 + threadIdx.x;

    if (t < 384) {
        // layer1 sign weights, slope-folded, float4-padded: s1f[co*12 + k], k<9
        int co = t / 12, k = t % 12;
        float val = 0.f;
        if (k < 9) {
            float iv = g1[co] * rsqrtf(v1[co] + BN_EPS);
            float d = (iv < 0.f) ? -1.f : 1.f;
            val = ((w1[co * 9 + k] >= 0.f) ? 1.f : -1.f) * d;
        }
        s1f[t] = val;
    } else if (t < 416) {
        // layer1 fp threshold via total-order bisection: bit = (sum' >= T1[co])
        int co = t - 384;
        float iv = g1[co] * rsqrtf(v1[co] + BN_EPS);
        float sh = be1[co] - m1[co] * iv;
        float B = b1[co];
        bool flip = (iv < 0.f);
        auto pred = [&](float sp) {
            float sum = flip ? -sp : sp;
            return bn_eval(sum, B, iv, sh) >= 0.f;
        };
        u32 lo = f2k(-3.0e38f), hi = f2k(3.0e38f);
        float Tv;
        if (pred(k2f(lo))) Tv = k2f(lo);
        else if (!pred(k2f(hi))) Tv = __uint_as_float(0x7F800000u);
        else {
            while (hi - lo > 1u) {
                u32 mid = lo + ((hi - lo) >> 1);
                if (pred(k2f(mid))) hi = mid; else lo = mid;
            }
            Tv = k2f(hi);
        }
        T1[co] = Tv;
    } else if (t < 800) {
        // layer2 B as i8 (+-1, sign-folded by sign(iv2)): [q][n] q=kw*2+half
        int idx = t - 416;           // [0,384)
        int q = idx >> 6, n = idx & 63;
        float iv = g2[n] * rsqrtf(v2[n] + BN_EPS);
        bool flip = (iv < 0.f);
        int kw = q >> 1, ci0 = (q & 1) * 16;
        u32 wd[4] = {0, 0, 0, 0};
        for (int j = 0; j < 16; ++j) {
            int ci = ci0 + j;
            bool pos = (w2[(n * 32 + ci) * 3 + kw] >= 0.f) != flip;
            u32 byte = pos ? 0x01u : 0xFFu;
            wd[j >> 2] |= byte << (8 * (j & 3));
        }
        b2i8[idx] = make_uint4(wd[0], wd[1], wd[2], wd[3]);
    } else if (t < 864) {
        // layer2 integer conv-threshold: bit <=> conv' >= C2[co]
        // conv' over <=96 sign-folded +-1 taps (0 at pads) -> even in [-96,96]
        int co = t - 800;
        float iv = g2[co] * rsqrtf(v2[co] + BN_EPS);
        float sh = be2[co] - m2[co] * iv;
        float B = b2[co];
        int C = 1000;
        if (iv >= 0.f) {
            for (int v = -96; v <= 96; v += 2)
                if (bn_eval((float)v, B, iv, sh) >= 0.f) { C = v; break; }
        } else {
            for (int v = 96; v >= -96; v -= 2)
                if (bn_eval((float)v, B, iv, sh) >= 0.f) { C = -v; break; }
        }
        C2[co] = C;
    } else if (t < 2400) {
        // layer3 B as i8: [q][n], q in [0,12): kw=q>>2, ci=(q&3)*16+j
        int idx = t - 864;
        int q = idx >> 7, n = idx & 127;
        float iv = g3[n] * rsqrtf(v3[n] + BN_EPS);
        bool flip = (iv < 0.f);
        int kw = q >> 2, ci0 = (q & 3) * 16;
        u32 wd[4] = {0, 0, 0, 0};
        for (int j = 0; j < 16; ++j) {
            int ci = ci0 + j;
            bool pos = (w3[(n * 64 + ci) * 3 + kw] >= 0.f) != flip;
            u32 byte = pos ? 0x01u : 0xFFu;
            wd[j >> 2] |= byte << (8 * (j & 3));
        }
        b3i8[idx] = make_uint4(wd[0], wd[1], wd[2], wd[3]);
    } else if (t < 2528) {
        // layer3 integer conv-threshold: bit <=> conv' >= C3[co]
        int co = t - 2400;
        float iv = g3[co] * rsqrtf(v3[co] + BN_EPS);
        float sh = be3[co] - m3[co] * iv;
        float B = b3[co];
        int C = 1000;
        if (iv >= 0.f) {
            for (int v = -192; v <= 192; v += 2)
                if (bn_eval((float)v, B, iv, sh) >= 0.f) { C = v; break; }
        } else {
            for (int v = 192; v >= -192; v -= 2)
                if (bn_eval((float)v, B, iv, sh) >= 0.f) { C = -v; break; }
        }
        C3[co] = C;
    } else if (t < 4064) {
        // layer4 packed weights
        int idx = t - 2528;
        int j = idx & 1, ch = idx >> 1;
        int co = ch / 6, h = ch % 6;
        float iv = g4[co] * rsqrtf(v4[co] + BN_EPS);
        bool flip = (iv < 0.f);
        u64 wb = 0;
        for (int cb = 0; cb < 64; ++cb) {
            int ci = j * 64 + cb;
            wb |= (u64)((w4[(co * 128 + ci) * 6 + h] >= 0.f) != flip) << cb;
        }
        wt4[idx] = wb;
    } else if (t < 4192) {
        // layer4 thresholds
        int co = t - 4064;
        float iv = g4[co] * rsqrtf(v4[co] + BN_EPS);
        float sh = be4[co] - m4[co] * iv;
        float B = b4[co];
        bool flip = (iv < 0.f);
        int T = -1;
        for (int p = 0; p <= 768; ++p) {
            int conv = flip ? (2 * p - 768) : (768 - 2 * p);
            float y = bn_eval((float)conv, B, iv, sh);
            if ((y >= 0.f) && (T == p - 1)) T = p;
        }
        T4[co] = T;
    } else if (t < 4512) {
        // fc weights
        int idx = t - 4192;
        int o = idx / 32, wi = idx % 32;
        u64 wb = 0;
        for (int fb = 0; fb < 64; ++fb)
            wb |= (u64)(wf[o * 2048 + wi * 64 + fb] >= 0.f) << fb;
        wtf[idx] = wb;
    }
}

// ---------------- layer 1: fp32 conv + threshold sign + pool-OR ----------------
// thread = (co = t&31, row = t>>5); weights in VGPRs; fully-unrolled sliding
// window; ballot assembles per-position 32-co words (2 rows per wave).
#define L1_ROWS 8
__global__ __launch_bounds__(256) void layer1_kernel(
    const float* __restrict__ x, const float4* __restrict__ s1p, const float* __restrict__ T1,
    u32* __restrict__ a1) {
    __shared__ float sX[L1_ROWS][144];   // [row][4 zeros | 128 x | 12 zeros]
    int t = threadIdx.x;
    int bh0 = blockIdx.x * L1_ROWS;
    for (int i = t; i < L1_ROWS * 144; i += 256) {
        int r = i / 144, c = i % 144;
        float v = 0.f;
        if (c >= 4 && c < 132) v = x[(size_t)(bh0 + r) * 128 + (c - 4)];
        sX[r][c] = v;
    }
    int co = t & 31, lane = t & 63;
    float4 wa = s1p[co * 3 + 0];
    float4 wb = s1p[co * 3 + 1];
    float wc = s1p[co * 3 + 2].x;
    float Tt = T1[co];
    __syncthreads();

    int rr = t >> 5;
    const float* xr = sX[rr];
    float4 A0 = *(const float4*)&xr[0];
    float4 A1 = *(const float4*)&xr[4];
    float4 A2 = *(const float4*)&xr[8];
    u32 myword = 0;
#pragma unroll
    for (int wp = 0; wp < 32; ++wp) {
        float sum0 = 0.f, sum1 = 0.f;
        sum0 = fmaf(wa.x, A0.x, sum0);  sum1 = fmaf(wa.x, A0.z, sum1);
        sum0 = fmaf(wa.y, A0.y, sum0);  sum1 = fmaf(wa.y, A0.w, sum1);
        sum0 = fmaf(wa.z, A0.z, sum0);  sum1 = fmaf(wa.z, A1.x, sum1);
        sum0 = fmaf(wa.w, A0.w, sum0);  sum1 = fmaf(wa.w, A1.y, sum1);
        sum0 = fmaf(wb.x, A1.x, sum0);  sum1 = fmaf(wb.x, A1.z, sum1);
        sum0 = fmaf(wb.y, A1.y, sum0);  sum1 = fmaf(wb.y, A1.w, sum1);
        sum0 = fmaf(wb.z, A1.z, sum0);  sum1 = fmaf(wb.z, A2.x, sum1);
        sum0 = fmaf(wb.w, A1.w, sum0);  sum1 = fmaf(wb.w, A2.y, sum1);
        sum0 = fmaf(wc,   A2.x, sum0);  sum1 = fmaf(wc,   A2.z, sum1);
        bool pred = fmaxf(sum0, sum1) >= Tt;   // == (sum0>=T)||(sum1>=T), finite sums
        u64 mk = __ballot(pred);
        u32 hw = (lane < 32) ? (u32)mk : (u32)(mk >> 32);
        if ((lane & 31) == wp) myword = hw;
        A0 = A1; A1 = A2;
        A2 = *(const float4*)&xr[4 * wp + 12];
    }
    // lane L of wave W holds word for row 2W + (L>=32), position L&31
    a1[(size_t)(bh0 + ((t >> 6) << 1) + (lane >> 5)) * 32 + (lane & 31)] = myword;
}

// ---------------- fused layer2 + layer3: i8 MFMA, a2 stays in registers ----------------
// One wave per row. L2: M=32 w, N=64 co, K=96 (3 taps x 32 ci) -> 2x3 MFMA,
// ballot epilogue (no pooling) -> per-lane a2 half-words. shfl-combine to u64,
// then the verified L3 body (4x6 MFMA + pooled ballot epilogue) -> a3.
#define L23_ROWS 4
__global__ __launch_bounds__(256) void layer23_kernel(
    const u32* __restrict__ a1, const uint4* __restrict__ b2i8, const int* __restrict__ C2,
    const uint4* __restrict__ b3i8, const int* __restrict__ C3, u32* __restrict__ a3u32) {
    __shared__ uint4 sB2[384];        // 6144 B
    __shared__ uint4 sB3[12 * 128];   // 24576 B
    __shared__ u64 sLUT[256];         // 2048 B
    __shared__ int sC2[64];
    __shared__ int sC3[128];
    int t = threadIdx.x;
    for (int i = t; i < 384; i += 256) sB2[i] = b2i8[i];
    for (int i = t; i < 1536; i += 256) sB3[i] = b3i8[i];
    {
        u32 b = t & 255;
        u64 e = 0;
#pragma unroll
        for (int j = 0; j < 8; ++j)
            e |= (((b >> j) & 1) ? 0x01ull : 0xFFull) << (8 * j);
        if (t < 256) sLUT[t] = e;
    }
    if (t < 64) sC2[t] = C2[t];
    if (t < 128) sC3[t] = C3[t];
    __syncthreads();

    int wv = t >> 6, lane = t & 63, m = lane & 31, half = lane >> 5;
    int rowBase = (blockIdx.x * 4 + wv) * L23_ROWS;
    const int prTab[8] = {0, 1, 4, 5, 8, 9, 12, 13};

    for (int r = 0; r < L23_ROWS; ++r) {
        int bh = rowBase + r;
        // ===== L2 =====
        u32 aw1 = a1[(size_t)bh * 32 + m];
        u32 a1m = __shfl(aw1, m - 1);     // m=0 -> masked below
        u32 a1p = __shfl(aw1, m + 1);     // m=31 -> masked below
        v4i A2f[3];
#pragma unroll
        for (int kw = 0; kw < 3; ++kw) {
            u32 word = (kw == 0) ? a1m : ((kw == 1) ? aw1 : a1p);
            bool valid = !((kw == 0 && m == 0) || (kw == 2 && m == 31));
            u32 bits = (word >> (half * 16)) & 0xFFFFu;
            u64 lo = sLUT[bits & 0xFF];
            u64 hi = sLUT[bits >> 8];
            if (!valid) { lo = 0; hi = 0; }
            union { u64 q[2]; v4i v; } u;
            u.q[0] = lo; u.q[1] = hi;
            A2f[kw] = u.v;
        }
        u32 outv2 = 0;
#pragma unroll
        for (int nt2 = 0; nt2 < 2; ++nt2) {
            v16i acc;
#pragma unroll
            for (int i = 0; i < 16; ++i) acc[i] = 0;
#pragma unroll
            for (int kw = 0; kw < 3; ++kw) {
                union { uint4 u4; v4i v; } bu;
                bu.u4 = sB2[(kw * 2 + half) * 64 + nt2 * 32 + m];
                acc = __builtin_amdgcn_mfma_i32_32x32x32_i8(A2f[kw], bu.v, acc, 0, 0, 0);
            }
            int tc = sC2[nt2 * 32 + m];
#pragma unroll
            for (int reg = 0; reg < 16; ++reg) {
                bool c = (acc[reg] >= tc);
                u64 mk = __ballot(c);
                int r0 = (reg & 3) + 8 * (reg >> 2);   // row for half 0; half 1 = r0+4
                int LA = nt2 * 32 + r0;
                int LB = nt2 * 32 + r0 + 4;
                outv2 = (lane == LA) ? (u32)mk : outv2;
                outv2 = (lane == LB) ? (u32)(mk >> 32) : outv2;
            }
        }
        // lane L = (nt2' = L>>5, position p = L&31) holds a2 half-word
        u32 lo32 = __shfl(outv2, m);        // nt0 word for position m
        u32 hi32 = __shfl(outv2, 32 + m);   // nt1 word for position m
        u64 aw = ((u64)hi32 << 32) | (u64)lo32;

        // ===== L3 (verified body) =====
        u64 wm1 = __shfl(aw, m - 1);
        u64 wp1 = __shfl(aw, m + 1);
        v4i A[6];
#pragma unroll
        for (int kk = 0; kk < 6; ++kk) {
            const int kw = kk >> 1;
            u64 word = (kw == 0) ? wm1 : ((kw == 1) ? aw : wp1);
            bool valid = !((kw == 0 && m == 0) || (kw == 2 && m == 31));
            int ci0 = ((kk & 1) << 5) + (half << 4);
            u32 bits = (u32)(word >> ci0) & 0xFFFFu;
            u64 lo = sLUT[bits & 0xFF];
            u64 hi = sLUT[bits >> 8];
            if (!valid) { lo = 0; hi = 0; }
            union { u64 q[2]; v4i v; } u;
            u.q[0] = lo; u.q[1] = hi;
            A[kk] = u.v;
        }
        u32 outv = 0;
#pragma unroll
        for (int nt = 0; nt < 4; ++nt) {
            v16i acc;
#pragma unroll
            for (int i = 0; i < 16; ++i) acc[i] = 0;
#pragma unroll
            for (int kk = 0; kk < 6; ++kk) {
                int q = kk * 2 + half;
                union { uint4 u4; v4i v; } bu;
                bu.u4 = sB3[q * 128 + nt * 32 + m];
                acc = __builtin_amdgcn_mfma_i32_32x32x32_i8(A[kk], bu.v, acc, 0, 0, 0);
            }
            int tc = sC3[nt * 32 + m];
#pragma unroll
            for (int rp = 0; rp < 8; ++rp) {
                bool c = (acc[2 * rp] >= tc) || (acc[2 * rp + 1] >= tc);
                u64 mk = __ballot(c);
                int LA = (nt << 4) | prTab[rp];
                int LB = LA + 2;
                outv = (lane == LA) ? (u32)mk : outv;
                outv = (lane == LB) ? (u32)(mk >> 32) : outv;
            }
        }
        a3u32[(size_t)bh * 64 + ((lane & 15) << 2) + (lane >> 4)] = outv;
    }
}

// ---------------- layer 4 (6x1 conv) + FC (2048->10) ----------------
__global__ __launch_bounds__(256) void layer4_fc_kernel(
    const u64* __restrict__ a3, const u64* __restrict__ wt4, const int* __restrict__ T4,
    const u64* __restrict__ wtf, const float* __restrict__ bf, float* __restrict__ out) {
    __shared__ u64 sW4[1536];
    __shared__ u64 sWf[320];
    __shared__ u64 sFeat[16][32];
    __shared__ int sT[128];
    __shared__ float sBf[10];
    int t = threadIdx.x;
    {
        ulonglong2* d = (ulonglong2*)sW4;
        const ulonglong2* s = (const ulonglong2*)wt4;
        for (int i = t; i < 768; i += 256) d[i] = s[i];
        ulonglong2* df = (ulonglong2*)sWf;
        const ulonglong2* sf = (const ulonglong2*)wtf;
        if (t < 160) df[t] = sf[t];
    }
    if (t < 128) sT[t] = T4[t];
    if (t < 10) sBf[t] = bf[t];
    __syncthreads();
    int bb = t >> 4, w = t & 15, lane = t & 63, g = lane >> 4;
    int b = blockIdx.x * 16 + bb;
    u64 av[12];
#pragma unroll
    for (int h = 0; h < 6; ++h) {
        av[h * 2 + 0] = a3[(size_t)b * 192 + h * 32 + w * 2 + 0];
        av[h * 2 + 1] = a3[(size_t)b * 192 + h * 32 + w * 2 + 1];
    }
    u64 acc = 0;
#pragma unroll 8
    for (int c = 0; c < 128; ++c) {
        const u64* wr = &sW4[c * 12];
        int p = 0;
#pragma unroll
        for (int q = 0; q < 12; ++q) p += __popcll(av[q] ^ wr[q]);
        u64 mk = __ballot(p <= sT[c]);
        u64 field = (mk >> (g * 16)) & 0xFFFFull;
        acc |= field << ((c & 3) << 4);
        if ((c & 3) == 3) {
            if (w == 0) sFeat[bb][c >> 2] = acc;
            acc = 0;
        }
    }
    __syncthreads();
    if (t < 160) {
        int fb = t / 10, o = t % 10;
        int p = 0;
#pragma unroll
        for (int wi = 0; wi < 32; ++wi) p += __popcll(sFeat[fb][wi] ^ sWf[o * 32 + wi]);
        out[(size_t)(blockIdx.x * 16 + fb) * 10 + o] = __fadd_rn((float)(2048 - 2 * p), sBf[o]);
    }
}

// ---------------- launch ----------------
extern "C" void kernel_launch(void* const* d_in, const int* in_sizes, int n_in,
                              void* d_out, int out_size, void* d_ws, size_t ws_size,
                              hipStream_t stream) {
    const float* x  = (const float*)d_in[0];
    const float* w1 = (const float*)d_in[1];  const float* b1 = (const float*)d_in[2];
    const float* w2 = (const float*)d_in[3];  const float* b2 = (const float*)d_in[4];
    const float* w3 = (const float*)d_in[5];  const float* b3 = (const float*)d_in[6];
    const float* w4 = (const float*)d_in[7];  const float* b4 = (const float*)d_in[8];
    const float* g1 = (const float*)d_in[9];  const float* be1 = (const float*)d_in[10];
    const float* m1 = (const float*)d_in[11]; const float* v1 = (const float*)d_in[12];
    const float* g2 = (const float*)d_in[13]; const float* be2 = (const float*)d_in[14];
    const float* m2 = (const float*)d_in[15]; const float* v2 = (const float*)d_in[16];
    const float* g3 = (const float*)d_in[17]; const float* be3 = (const float*)d_in[18];
    const float* m3 = (const float*)d_in[19]; const float* v3 = (const float*)d_in[20];
    const float* g4 = (const float*)d_in[21]; const float* be4 = (const float*)d_in[22];
    const float* m4 = (const float*)d_in[23]; const float* v4 = (const float*)d_in[24];
    const float* wf = (const float*)d_in[25]; const float* bf = (const float*)d_in[26];
    float* out = (float*)d_out;

    char* ws = (char*)d_ws;
    u32* a1 = (u32*)(ws + 0);                 // 8192*6*32 u32 = 6291456 B
    u64* a3 = (u64*)(ws + 6291456);           // 8192*6*16*2 u64 = 12582912 B
    const size_t S = 18874368;
    uint4* b2i8 = (uint4*)(ws + S + 0);       // 6144 B
    uint4* b3i8 = (uint4*)(ws + S + 6144);    // 24576 B
    u64*  wt4  = (u64*) (ws + S + 30720);     // 12288 B
    u64*  wtf  = (u64*) (ws + S + 43008);     // 2560 B
    float* s1f = (float*)(ws + S + 45568);    // 1536 B
    float* T1  = (float*)(ws + S + 47104);    // 128 B
    int*  C2   = (int*)  (ws + S + 47232);    // 256 B
    int*  C3   = (int*)  (ws + S + 47488);    // 512 B
    int*  T4   = (int*)  (ws + S + 48000);    // 512 B

    prep_all<<<18, 256, 0, stream>>>(w1, b1, w2, b2, w3, b3, w4, b4, wf,
                                     g1, be1, m1, v1, g2, be2, m2, v2,
                                     g3, be3, m3, v3, g4, be4, m4, v4,
                                     s1f, T1, b2i8, C2, b3i8, C3, wt4, T4, wtf);

    layer1_kernel<<<(BATCH * 6) / L1_ROWS, 256, 0, stream>>>(
        x, (const float4*)s1f, T1, a1);
    layer23_kernel<<<(BATCH * 6) / (4 * L23_ROWS), 256, 0, stream>>>(
        a1, b2i8, C2, b3i8, C3, (u32*)a3);
    layer4_fc_kernel<<<BATCH / 16, 256, 0, stream>>>(a3, wt4, T4, wtf, bf, out);
}

// Round 10
// 270.418 us; speedup vs baseline: 1.0602x; 1.0516x over previous
//
#include <hip/hip_runtime.h>
#include <cstdint>
#include <cstddef>

#define BN_EPS 1e-5f
#define BATCH 8192

typedef unsigned long long u64;
typedef uint32_t u32;
typedef int v4i __attribute__((ext_vector_type(4)));
typedef int v16i __attribute__((ext_vector_type(16)));

// float <-> total-order key (ascending with float order on finites)
__device__ __forceinline__ u32 f2k(float f) {
    u32 u = __float_as_uint(f);
    return (u >> 31) ? ~u : (u | 0x80000000u);
}
__device__ __forceinline__ float k2f(u32 k) {
    u32 u = (k & 0x80000000u) ? (k ^ 0x80000000u) : ~k;
    return __uint_as_float(u);
}
// exact fp32 BN chain — bit-identical to the reference epilogue semantics
__device__ __forceinline__ float bn_eval(float conv, float B, float iv, float sh) {
    return __fadd_rn(__fmul_rn(__fadd_rn(conv, B), iv), sh);
}

// ---------------- one merged prep kernel (R8-verified) ----------------
__global__ __launch_bounds__(256) void prep_all(
    const float* w1, const float* b1, const float* w2, const float* b2,
    const float* w3, const float* b3, const float* w4, const float* b4,
    const float* wf,
    const float* g1, const float* be1, const float* m1, const float* v1,
    const float* g2, const float* be2, const float* m2, const float* v2,
    const float* g3, const float* be3, const float* m3, const float* v3,
    const float* g4, const float* be4, const float* m4, const float* v4,
    float* s1f, float* T1, u32* wt2w, int* T2,
    uint4* b3i8, int* C3, u64* wt4, int* T4, u64* wtf) {
    int t = blockIdx.x * 256 + threadIdx.x;

    if (t < 384) {
        int co = t / 12, k = t % 12;
        float val = 0.f;
        if (k < 9) {
            float iv = g1[co] * rsqrtf(v1[co] + BN_EPS);
            float d = (iv < 0.f) ? -1.f : 1.f;
            val = ((w1[co * 9 + k] >= 0.f) ? 1.f : -1.f) * d;
        }
        s1f[t] = val;
    } else if (t < 416) {
        int co = t - 384;
        float iv = g1[co] * rsqrtf(v1[co] + BN_EPS);
        float sh = be1[co] - m1[co] * iv;
        float B = b1[co];
        bool flip = (iv < 0.f);
        auto pred = [&](float sp) {
            float sum = flip ? -sp : sp;
            return bn_eval(sum, B, iv, sh) >= 0.f;
        };
        u32 lo = f2k(-3.0e38f), hi = f2k(3.0e38f);
        float Tv;
        if (pred(k2f(lo))) Tv = k2f(lo);
        else if (!pred(k2f(hi))) Tv = __uint_as_float(0x7F800000u);
        else {
            while (hi - lo > 1u) {
                u32 mid = lo + ((hi - lo) >> 1);
                if (pred(k2f(mid))) hi = mid; else lo = mid;
            }
            Tv = k2f(hi);
        }
        T1[co] = Tv;
    } else if (t < 608) {
        int idx = t - 416;
        int co = idx / 3, kw = idx % 3;
        float iv = g2[co] * rsqrtf(v2[co] + BN_EPS);
        bool flip = (iv < 0.f);
        u32 wb = 0;
        for (int ci = 0; ci < 32; ++ci)
            wb |= (u32)((w2[(co * 32 + ci) * 3 + kw] >= 0.f) != flip) << ci;
        wt2w[co * 4 + kw] = wb;
    } else if (t < 800) {
        int idx = t - 608;
        int co = idx & 63, cls = idx >> 6;
        float iv = g2[co] * rsqrtf(v2[co] + BN_EPS);
        float sh = be2[co] - m2[co] * iv;
        float B = b2[co];
        bool flip = (iv < 0.f);
        int spur = 0, nv = 3;
        if (cls == 1) { nv = 2; for (int ci = 0; ci < 32; ++ci) spur += (int)((w2[(co * 32 + ci) * 3 + 0] >= 0.f) != flip); }
        if (cls == 2) { nv = 2; for (int ci = 0; ci < 32; ++ci) spur += (int)((w2[(co * 32 + ci) * 3 + 2] >= 0.f) != flip); }
        int maxp = 32 * nv + spur;
        int T = -1;
        for (int p = 0; p <= maxp; ++p) {
            int conv = flip ? (2 * (p - spur) - 32 * nv) : (32 * nv - 2 * (p - spur));
            float y = bn_eval((float)conv, B, iv, sh);
            if ((y >= 0.f) && (T == p - 1)) T = p;
        }
        T2[cls * 64 + co] = T;
    } else if (t < 2336) {
        int idx = t - 800;
        int q = idx >> 7, n = idx & 127;
        float iv = g3[n] * rsqrtf(v3[n] + BN_EPS);
        bool flip = (iv < 0.f);
        int kw = q >> 2, ci0 = (q & 3) * 16;
        u32 wd[4] = {0, 0, 0, 0};
        for (int j = 0; j < 16; ++j) {
            int ci = ci0 + j;
            bool pos = (w3[(n * 64 + ci) * 3 + kw] >= 0.f) != flip;
            u32 byte = pos ? 0x01u : 0xFFu;
            wd[j >> 2] |= byte << (8 * (j & 3));
        }
        b3i8[idx] = make_uint4(wd[0], wd[1], wd[2], wd[3]);
    } else if (t < 2464) {
        int co = t - 2336;
        float iv = g3[co] * rsqrtf(v3[co] + BN_EPS);
        float sh = be3[co] - m3[co] * iv;
        float B = b3[co];
        int C = 1000;
        if (iv >= 0.f) {
            for (int v = -192; v <= 192; v += 2)
                if (bn_eval((float)v, B, iv, sh) >= 0.f) { C = v; break; }
        } else {
            for (int v = 192; v >= -192; v -= 2)
                if (bn_eval((float)v, B, iv, sh) >= 0.f) { C = -v; break; }
        }
        C3[co] = C;
    } else if (t < 4000) {
        int idx = t - 2464;
        int j = idx & 1, ch = idx >> 1;
        int co = ch / 6, h = ch % 6;
        float iv = g4[co] * rsqrtf(v4[co] + BN_EPS);
        bool flip = (iv < 0.f);
        u64 wb = 0;
        for (int cb = 0; cb < 64; ++cb) {
            int ci = j * 64 + cb;
            wb |= (u64)((w4[(co * 128 + ci) * 6 + h] >= 0.f) != flip) << cb;
        }
        wt4[idx] = wb;
    } else if (t < 4128) {
        int co = t - 4000;
        float iv = g4[co] * rsqrtf(v4[co] + BN_EPS);
        float sh = be4[co] - m4[co] * iv;
        float B = b4[co];
        bool flip = (iv < 0.f);
        int T = -1;
        for (int p = 0; p <= 768; ++p) {
            int conv = flip ? (2 * p - 768) : (768 - 2 * p);
            float y = bn_eval((float)conv, B, iv, sh);
            if ((y >= 0.f) && (T == p - 1)) T = p;
        }
        T4[co] = T;
    } else if (t < 4448) {
        int idx = t - 4128;
        int o = idx / 32, wi = idx % 32;
        u64 wb = 0;
        for (int fb = 0; fb < 64; ++fb)
            wb |= (u64)(wf[o * 2048 + wi * 64 + fb] >= 0.f) << fb;
        wtf[idx] = wb;
    }
}

// ---------------- fused L1+L2+L3: row-local chain, a1/a2 in LDS only ----------------
// Block = 24 rows. 3 chunks of 8 rows: L1 (verified ballot body) -> sA1,
// L2 (verified popcount body) -> sA2; then L3 MFMA (verified body), 4 waves
// x 6 rows, writing a3 to global. LDS total 40.7 KB -> 3 blocks/CU.
#define RB 24
__global__ __launch_bounds__(256, 3) void mega123_kernel(
    const float* __restrict__ x, const float4* __restrict__ s1p, const float* __restrict__ T1g,
    const uint4* __restrict__ wt2v, const int* __restrict__ T2g,
    const uint4* __restrict__ b3i8, const int* __restrict__ C3g,
    u32* __restrict__ a3u32) {
    __shared__ uint4 sB3[1536];     // 24576 B
    __shared__ u64 sLUT[256];       // 2048 B
    __shared__ int sC3[128];        // 512 B
    __shared__ uint4 sW2[64];       // 1024 B
    __shared__ int sT2[192];        // 768 B
    __shared__ float sX[8][144];    // 4608 B
    __shared__ u32 sA1[8][32];      // 1024 B
    __shared__ u64 sA2[RB][32];     // 6144 B
    int t = threadIdx.x;
    for (int i = t; i < 1536; i += 256) sB3[i] = b3i8[i];
    {
        u32 b = t & 255;
        u64 e = 0;
#pragma unroll
        for (int j = 0; j < 8; ++j)
            e |= (((b >> j) & 1) ? 0x01ull : 0xFFull) << (8 * j);
        if (t < 256) sLUT[t] = e;
    }
    if (t < 128) sC3[t] = C3g[t];
    if (t < 64) sW2[t] = wt2v[t];
    if (t < 192) sT2[t] = T2g[t];

    int co = t & 31, lane = t & 63;
    float4 wa = s1p[co * 3 + 0];
    float4 wb = s1p[co * 3 + 1];
    float wc = s1p[co * 3 + 2].x;
    float Tt = T1g[co];

    int bh0 = blockIdx.x * RB;
    for (int ch = 0; ch < 3; ++ch) {
        __syncthreads();                       // protect sX/sA1 reuse across chunks
        for (int i = t; i < 8 * 144; i += 256) {
            int r = i / 144, c = i % 144;
            float v = 0.f;
            if (c >= 4 && c < 132) v = x[(size_t)(bh0 + ch * 8 + r) * 128 + (c - 4)];
            sX[r][c] = v;
        }
        __syncthreads();
        // ----- L1 (verified R9 body; output to LDS with same lane mapping) -----
        {
            int rr = t >> 5;
            const float* xr = sX[rr];
            float4 A0 = *(const float4*)&xr[0];
            float4 A1 = *(const float4*)&xr[4];
            float4 A2 = *(const float4*)&xr[8];
            u32 myword = 0;
#pragma unroll
            for (int wp = 0; wp < 32; ++wp) {
                float sum0 = 0.f, sum1 = 0.f;
                sum0 = fmaf(wa.x, A0.x, sum0);  sum1 = fmaf(wa.x, A0.z, sum1);
                sum0 = fmaf(wa.y, A0.y, sum0);  sum1 = fmaf(wa.y, A0.w, sum1);
                sum0 = fmaf(wa.z, A0.z, sum0);  sum1 = fmaf(wa.z, A1.x, sum1);
                sum0 = fmaf(wa.w, A0.w, sum0);  sum1 = fmaf(wa.w, A1.y, sum1);
                sum0 = fmaf(wb.x, A1.x, sum0);  sum1 = fmaf(wb.x, A1.z, sum1);
                sum0 = fmaf(wb.y, A1.y, sum0);  sum1 = fmaf(wb.y, A1.w, sum1);
                sum0 = fmaf(wb.z, A1.z, sum0);  sum1 = fmaf(wb.z, A2.x, sum1);
                sum0 = fmaf(wb.w, A1.w, sum0);  sum1 = fmaf(wb.w, A2.y, sum1);
                sum0 = fmaf(wc,   A2.x, sum0);  sum1 = fmaf(wc,   A2.z, sum1);
                bool pred = fmaxf(sum0, sum1) >= Tt;
                u64 mk = __ballot(pred);
                u32 hw = (lane < 32) ? (u32)mk : (u32)(mk >> 32);
                if ((lane & 31) == wp) myword = hw;
                A0 = A1; A1 = A2;
                A2 = *(const float4*)&xr[4 * wp + 12];
            }
            sA1[((t >> 6) << 1) + (lane >> 5)][lane & 31] = myword;
        }
        __syncthreads();
        // ----- L2 (verified R5 body; LDS in, LDS out) -----
        {
            int r = t >> 5, wp = t & 31;
            u32 am = sA1[r][wp];
            u32 al = (wp > 0) ? sA1[r][wp - 1] : 0u;
            u32 ar = (wp < 31) ? sA1[r][wp + 1] : 0u;
            const int* Tp = &sT2[(wp == 0) ? 64 : ((wp == 31) ? 128 : 0)];
            u64 word2 = 0;
#pragma unroll
            for (int c = 0; c < 64; ++c) {
                uint4 w2v = sW2[c];
                int p = __popc(al ^ w2v.x) + __popc(am ^ w2v.y) + __popc(ar ^ w2v.z);
                word2 |= (u64)(p <= Tp[c]) << c;
            }
            sA2[ch * 8 + r][wp] = word2;
        }
    }
    __syncthreads();

    // ----- L3 (verified MFMA body; neighbors via guarded LDS reads) -----
    int wq = t >> 6, m = lane & 31, half = lane >> 5;
    const int prTab[8] = {0, 1, 4, 5, 8, 9, 12, 13};
    for (int r6 = 0; r6 < 6; ++r6) {
        int row = wq * 6 + r6;
        u64 aw = sA2[row][m];
        u64 wm1 = (m > 0) ? sA2[row][m - 1] : 0ull;
        u64 wp1 = (m < 31) ? sA2[row][m + 1] : 0ull;

        v4i A[6];
#pragma unroll
        for (int kk = 0; kk < 6; ++kk) {
            const int kw = kk >> 1;
            u64 word = (kw == 0) ? wm1 : ((kw == 1) ? aw : wp1);
            bool valid = !((kw == 0 && m == 0) || (kw == 2 && m == 31));
            int ci0 = ((kk & 1) << 5) + (half << 4);
            u32 bits = (u32)(word >> ci0) & 0xFFFFu;
            u64 lo = sLUT[bits & 0xFF];
            u64 hi = sLUT[bits >> 8];
            if (!valid) { lo = 0; hi = 0; }
            union { u64 q[2]; v4i v; } u;
            u.q[0] = lo; u.q[1] = hi;
            A[kk] = u.v;
        }
        u32 outv = 0;
#pragma unroll
        for (int nt = 0; nt < 4; ++nt) {
            v16i acc;
#pragma unroll
            for (int i = 0; i < 16; ++i) acc[i] = 0;
#pragma unroll
            for (int kk = 0; kk < 6; ++kk) {
                int q = kk * 2 + half;
                union { uint4 u4; v4i v; } bu;
                bu.u4 = sB3[q * 128 + nt * 32 + m];
                acc = __builtin_amdgcn_mfma_i32_32x32x32_i8(A[kk], bu.v, acc, 0, 0, 0);
            }
            int tc = sC3[nt * 32 + m];
#pragma unroll
            for (int rp = 0; rp < 8; ++rp) {
                bool c = (acc[2 * rp] >= tc) || (acc[2 * rp + 1] >= tc);
                u64 mk = __ballot(c);
                int LA = (nt << 4) | prTab[rp];
                int LB = LA + 2;
                outv = (lane == LA) ? (u32)mk : outv;
                outv = (lane == LB) ? (u32)(mk >> 32) : outv;
            }
        }
        a3u32[(size_t)(bh0 + row) * 64 + ((lane & 15) << 2) + (lane >> 4)] = outv;
    }
}

// ---------------- layer 4 (6x1 conv) + FC (2048->10), verified ----------------
__global__ __launch_bounds__(256) void layer4_fc_kernel(
    const u64* __restrict__ a3, const u64* __restrict__ wt4, const int* __restrict__ T4,
    const u64* __restrict__ wtf, const float* __restrict__ bf, float* __restrict__ out) {
    __shared__ u64 sW4[1536];
    __shared__ u64 sWf[320];
    __shared__ u64 sFeat[16][32];
    __shared__ int sT[128];
    __shared__ float sBf[10];
    int t = threadIdx.x;
    {
        ulonglong2* d = (ulonglong2*)sW4;
        const ulonglong2* s = (const ulonglong2*)wt4;
        for (int i = t; i < 768; i += 256) d[i] = s[i];
        ulonglong2* df = (ulonglong2*)sWf;
        const ulonglong2* sf = (const ulonglong2*)wtf;
        if (t < 160) df[t] = sf[t];
    }
    if (t < 128) sT[t] = T4[t];
    if (t < 10) sBf[t] = bf[t];
    __syncthreads();
    int bb = t >> 4, w = t & 15, lane = t & 63, g = lane >> 4;
    int b = blockIdx.x * 16 + bb;
    u64 av[12];
#pragma unroll
    for (int h = 0; h < 6; ++h) {
        av[h * 2 + 0] = a3[(size_t)b * 192 + h * 32 + w * 2 + 0];
        av[h * 2 + 1] = a3[(size_t)b * 192 + h * 32 + w * 2 + 1];
    }
    u64 acc = 0;
#pragma unroll 8
    for (int c = 0; c < 128; ++c) {
        const u64* wr = &sW4[c * 12];
        int p = 0;
#pragma unroll
        for (int q = 0; q < 12; ++q) p += __popcll(av[q] ^ wr[q]);
        u64 mk = __ballot(p <= sT[c]);
        u64 field = (mk >> (g * 16)) & 0xFFFFull;
        acc |= field << ((c & 3) << 4);
        if ((c & 3) == 3) {
            if (w == 0) sFeat[bb][c >> 2] = acc;
            acc = 0;
        }
    }
    __syncthreads();
    if (t < 160) {
        int fb = t / 10, o = t % 10;
        int p = 0;
#pragma unroll
        for (int wi = 0; wi < 32; ++wi) p += __popcll(sFeat[fb][wi] ^ sWf[o * 32 + wi]);
        out[(size_t)(blockIdx.x * 16 + fb) * 10 + o] = __fadd_rn((float)(2048 - 2 * p), sBf[o]);
    }
}

// ---------------- launch ----------------
extern "C" void kernel_launch(void* const* d_in, const int* in_sizes, int n_in,
                              void* d_out, int out_size, void* d_ws, size_t ws_size,
                              hipStream_t stream) {
    const float* x  = (const float*)d_in[0];
    const float* w1 = (const float*)d_in[1];  const float* b1 = (const float*)d_in[2];
    const float* w2 = (const float*)d_in[3];  const float* b2 = (const float*)d_in[4];
    const float* w3 = (const float*)d_in[5];  const float* b3 = (const float*)d_in[6];
    const float* w4 = (const float*)d_in[7];  const float* b4 = (const float*)d_in[8];
    const float* g1 = (const float*)d_in[9];  const float* be1 = (const float*)d_in[10];
    const float* m1 = (const float*)d_in[11]; const float* v1 = (const float*)d_in[12];
    const float* g2 = (const float*)d_in[13]; const float* be2 = (const float*)d_in[14];
    const float* m2 = (const float*)d_in[15]; const float* v2 = (const float*)d_in[16];
    const float* g3 = (const float*)d_in[17]; const float* be3 = (const float*)d_in[18];
    const float* m3 = (const float*)d_in[19]; const float* v3 = (const float*)d_in[20];
    const float* g4 = (const float*)d_in[21]; const float* be4 = (const float*)d_in[22];
    const float* m4 = (const float*)d_in[23]; const float* v4 = (const float*)d_in[24];
    const float* wf = (const float*)d_in[25]; const float* bf = (const float*)d_in[26];
    float* out = (float*)d_out;

    char* ws = (char*)d_ws;
    u64* a3 = (u64*)(ws + 0);                 // 8192*6*16*2 u64 = 12582912 B
    const size_t S = 12582912;
    uint4* b3i8 = (uint4*)(ws + S + 0);       // 24576 B
    u64*  wt4  = (u64*) (ws + S + 24576);     // 12288 B
    u64*  wtf  = (u64*) (ws + S + 36864);     // 2560 B
    u32*  wt2w = (u32*) (ws + S + 39424);     // 1024 B
    float* s1f = (float*)(ws + S + 40448);    // 1536 B
    float* T1  = (float*)(ws + S + 41984);    // 128 B
    int*  T2   = (int*)  (ws + S + 42112);    // 768 B
    int*  C3   = (int*)  (ws + S + 42880);    // 512 B
    int*  T4   = (int*)  (ws + S + 43392);    // 512 B

    prep_all<<<18, 256, 0, stream>>>(w1, b1, w2, b2, w3, b3, w4, b4, wf,
                                     g1, be1, m1, v1, g2, be2, m2, v2,
                                     g3, be3, m3, v3, g4, be4, m4, v4,
                                     s1f, T1, wt2w, T2, b3i8, C3, wt4, T4, wtf);

    mega123_kernel<<<(BATCH * 6) / RB, 256, 0, stream>>>(
        x, (const float4*)s1f, T1, (const uint4*)wt2w, T2, b3i8, C3, (u32*)a3);
    layer4_fc_kernel<<<BATCH / 16, 256, 0, stream>>>(a3, wt4, T4, wtf, bf, out);
}